// Round 1
// baseline (779.526 us; speedup 1.0000x reference)
//
#include <hip/hip_runtime.h>

#define N_NODES 50000
#define N_EDGES 600000
#define HID 128
#define LN_EPS 1e-5f

// ---------------- degree ----------------
__global__ __launch_bounds__(256) void k_init_deg(float* __restrict__ deg) {
    int i = blockIdx.x * 256 + threadIdx.x;
    if (i < N_NODES) deg[i] = 1.0f;   // self-loop
}

__global__ __launch_bounds__(256) void k_accum_deg(const int* __restrict__ ei, float* __restrict__ deg) {
    int e = blockIdx.x * 256 + threadIdx.x;
    if (e < N_EDGES) atomicAdd(&deg[ei[N_EDGES + e]], 1.0f);   // dst in-degree
}

__global__ __launch_bounds__(256) void k_dinv(float* __restrict__ deg) {
    int i = blockIdx.x * 256 + threadIdx.x;
    if (i < N_NODES) deg[i] = rsqrtf(deg[i]);   // in place: deg -> dinv
}

// ---------------- fp32 GEMM: C[M,128] = A[M,128] @ W[128,128] ----------------
// 256 threads = 16x16 thread grid, 128-row block tile, 8x8 register tile.
// sA stored k-major (sA[kk][r]) so inner-loop A reads are wave-broadcast.
__global__ __launch_bounds__(256) void k_gemm(const float* __restrict__ A,
                                              const float* __restrict__ W,
                                              float* __restrict__ C, int M) {
    __shared__ float sA[32][132];   // 32 k x 128 rows, stride 132 (16B-aligned rows, spread banks)
    const int tid = threadIdx.x;
    const int tx = tid & 15;    // col group: cols tx*8 .. +7
    const int ty = tid >> 4;    // row group: rows ty*8 .. +7
    const int row0 = blockIdx.x * 128;

    float acc[8][8];
#pragma unroll
    for (int i = 0; i < 8; ++i)
#pragma unroll
        for (int j = 0; j < 8; ++j) acc[i][j] = 0.0f;

    for (int k0 = 0; k0 < 128; k0 += 32) {
        // stage A chunk (128 rows x 32 k), transposing to k-major
        const int q = tid & 7;        // k-quad
        const int rb = tid >> 3;      // row 0..31
#pragma unroll
        for (int it = 0; it < 4; ++it) {
            const int r = rb + 32 * it;
            const int grow = row0 + r;
            float4 v = {0.f, 0.f, 0.f, 0.f};
            if (grow < M) v = *(const float4*)(A + (size_t)grow * HID + k0 + 4 * q);
            sA[4 * q + 0][r] = v.x;
            sA[4 * q + 1][r] = v.y;
            sA[4 * q + 2][r] = v.z;
            sA[4 * q + 3][r] = v.w;
        }
        __syncthreads();

#pragma unroll 8
        for (int kk = 0; kk < 32; ++kk) {
            const float4 a0 = *(const float4*)&sA[kk][ty * 8];
            const float4 a1 = *(const float4*)&sA[kk][ty * 8 + 4];
            const float4 w0 = *(const float4*)(W + (size_t)(k0 + kk) * HID + tx * 8);
            const float4 w1 = *(const float4*)(W + (size_t)(k0 + kk) * HID + tx * 8 + 4);
            const float a[8] = {a0.x, a0.y, a0.z, a0.w, a1.x, a1.y, a1.z, a1.w};
            const float w[8] = {w0.x, w0.y, w0.z, w0.w, w1.x, w1.y, w1.z, w1.w};
#pragma unroll
            for (int i = 0; i < 8; ++i)
#pragma unroll
                for (int j = 0; j < 8; ++j)
                    acc[i][j] = fmaf(a[i], w[j], acc[i][j]);
        }
        __syncthreads();
    }

#pragma unroll
    for (int i = 0; i < 8; ++i) {
        const int row = row0 + ty * 8 + i;
        if (row < M) {
            float4 o0 = {acc[i][0], acc[i][1], acc[i][2], acc[i][3]};
            float4 o1 = {acc[i][4], acc[i][5], acc[i][6], acc[i][7]};
            *(float4*)(C + (size_t)row * HID + tx * 8) = o0;
            *(float4*)(C + (size_t)row * HID + tx * 8 + 4) = o1;
        }
    }
}

// ---------------- edge scatter: agg[dst] += h[src] * dinv[src]*dinv[dst] ----------------
// one thread per (edge, feature); 128 consecutive threads share an edge -> coalesced
__global__ __launch_bounds__(256) void k_scatter(const int* __restrict__ ei,
                                                 const float* __restrict__ h,
                                                 const float* __restrict__ dinv,
                                                 float* __restrict__ agg) {
    const long gid = (long)blockIdx.x * 256 + threadIdx.x;
    const int e = (int)(gid >> 7);
    const int f = (int)(gid & 127);
    if (e < N_EDGES) {
        const int s = ei[e];
        const int d = ei[N_EDGES + e];
        const float w = dinv[s] * dinv[d];
        atomicAdd(&agg[(size_t)d * HID + f], h[(size_t)s * HID + f] * w);
    }
}

// ---------------- combine + LayerNorm + ReLU ----------------
// one wave (64 lanes) per row, 2 features per lane; 4 rows per 256-thread block
__global__ __launch_bounds__(256) void k_combine_ln(const float* __restrict__ agg,
                                                    const float* __restrict__ h,
                                                    const float* __restrict__ dinv,
                                                    const float* __restrict__ b,
                                                    const float* __restrict__ g,
                                                    const float* __restrict__ be,
                                                    float* __restrict__ out) {
    const int row = blockIdx.x * 4 + (threadIdx.x >> 6);
    const int lane = threadIdx.x & 63;
    if (row >= N_NODES) return;

    const float di = dinv[row];
    const float sn = di * di;
    const size_t base = (size_t)row * HID;

    float v0 = agg[base + lane]      + h[base + lane]      * sn + b[lane];
    float v1 = agg[base + lane + 64] + h[base + lane + 64] * sn + b[lane + 64];

    float s = v0 + v1;
    float ss = v0 * v0 + v1 * v1;
#pragma unroll
    for (int off = 32; off > 0; off >>= 1) {
        s  += __shfl_down(s, off);
        ss += __shfl_down(ss, off);
    }
    s  = __shfl(s, 0);
    ss = __shfl(ss, 0);

    const float mu = s * (1.0f / 128.0f);
    const float var = ss * (1.0f / 128.0f) - mu * mu;
    const float rs = rsqrtf(var + LN_EPS);

    const float o0 = (v0 - mu) * rs * g[lane]      + be[lane];
    const float o1 = (v1 - mu) * rs * g[lane + 64] + be[lane + 64];
    out[base + lane]      = fmaxf(o0, 0.0f);
    out[base + lane + 64] = fmaxf(o1, 0.0f);
}

// ---------------- launch ----------------
extern "C" void kernel_launch(void* const* d_in, const int* in_sizes, int n_in,
                              void* d_out, int out_size, void* d_ws, size_t ws_size,
                              hipStream_t stream) {
    (void)in_sizes; (void)n_in; (void)out_size; (void)ws_size;

    const float* x   = (const float*)d_in[0];
    const int*   ei  = (const int*)d_in[1];     // [2, E] row-major: src = ei[e], dst = ei[E+e]
    const float* W1  = (const float*)d_in[2];
    const float* b1  = (const float*)d_in[3];
    const float* g1  = (const float*)d_in[4];
    const float* be1 = (const float*)d_in[5];
    const float* W2  = (const float*)d_in[6];
    const float* b2  = (const float*)d_in[7];
    const float* g2  = (const float*)d_in[8];
    const float* be2 = (const float*)d_in[9];
    float* out = (float*)d_out;

    // workspace layout (floats): dinv [0,65536) | h [N*128] | agg [N*128]
    float* ws   = (float*)d_ws;
    float* dinv = ws;
    float* h    = ws + 65536;
    float* agg  = h + (size_t)N_NODES * HID;
    const size_t feat_bytes = (size_t)N_NODES * HID * sizeof(float);

    const int nb_nodes   = (N_NODES + 255) / 256;          // 196
    const int nb_edges   = (N_EDGES + 255) / 256;          // 2344
    const int nb_gemm    = (N_NODES + 127) / 128;          // 391
    const int nb_scatter = (int)(((long)N_EDGES * HID) / 256);  // 300000
    const int nb_ln      = (N_NODES + 3) / 4;              // 12500

    // degree -> dinv
    k_init_deg<<<nb_nodes, 256, 0, stream>>>(dinv);
    k_accum_deg<<<nb_edges, 256, 0, stream>>>(ei, dinv);
    k_dinv<<<nb_nodes, 256, 0, stream>>>(dinv);

    // ---- layer 1 ----  (y1 staged in d_out)
    k_gemm<<<nb_gemm, 256, 0, stream>>>(x, W1, h, N_NODES);
    hipMemsetAsync(agg, 0, feat_bytes, stream);
    k_scatter<<<nb_scatter, 256, 0, stream>>>(ei, h, dinv, agg);
    k_combine_ln<<<nb_ln, 256, 0, stream>>>(agg, h, dinv, b1, g1, be1, out);

    // ---- layer 2 ----
    k_gemm<<<nb_gemm, 256, 0, stream>>>(out, W2, h, N_NODES);
    hipMemsetAsync(agg, 0, feat_bytes, stream);
    k_scatter<<<nb_scatter, 256, 0, stream>>>(ei, h, dinv, agg);
    k_combine_ln<<<nb_ln, 256, 0, stream>>>(agg, h, dinv, b2, g2, be2, out);
}

// Round 2
// 489.195 us; speedup vs baseline: 1.5935x; 1.5935x over previous
//
#include <hip/hip_runtime.h>

#define N_NODES 50000
#define N_EDGES 600000
#define HID 128
#define LN_EPS 1e-5f

// ================= CSR build =================

// counts[dst]++ for every edge
__global__ __launch_bounds__(256) void k_hist(const int* __restrict__ ei, int* __restrict__ counts) {
    int e = blockIdx.x * 256 + threadIdx.x;
    if (e < N_EDGES) atomicAdd(&counts[ei[N_EDGES + e]], 1);
}

// exclusive prefix sum of counts[0..N) -> rowptr[0..N], single block of 1024
__global__ __launch_bounds__(1024) void k_scan(const int* __restrict__ counts, int* __restrict__ rowptr) {
    __shared__ int part[1024];
    const int tid = threadIdx.x;
    const int chunk = (N_NODES + 1023) / 1024;   // 49
    const int base = tid * chunk;

    int sum = 0;
    for (int i = 0; i < chunk; ++i) {
        int idx = base + i;
        if (idx < N_NODES) sum += counts[idx];
    }
    part[tid] = sum;
    __syncthreads();

    // Hillis-Steele inclusive scan over the 1024 partials
    for (int off = 1; off < 1024; off <<= 1) {
        int v = (tid >= off) ? part[tid - off] : 0;
        __syncthreads();
        part[tid] += v;
        __syncthreads();
    }

    int run = (tid == 0) ? 0 : part[tid - 1];
    for (int i = 0; i < chunk; ++i) {
        int idx = base + i;
        if (idx < N_NODES) {
            rowptr[idx] = run;
            run += counts[idx];
        }
    }
    if (tid == 1023) rowptr[N_NODES] = run;
}

// dinv[i] = rsqrt(in_degree + 1)   (self-loop)
__global__ __launch_bounds__(256) void k_dinv(const int* __restrict__ counts, float* __restrict__ dinv) {
    int i = blockIdx.x * 256 + threadIdx.x;
    if (i < N_NODES) dinv[i] = rsqrtf((float)counts[i] + 1.0f);
}

// scatter edge sources into CSR slots
__global__ __launch_bounds__(256) void k_place(const int* __restrict__ ei,
                                               const int* __restrict__ rowptr,
                                               int* __restrict__ cursor,
                                               int* __restrict__ esrc) {
    int e = blockIdx.x * 256 + threadIdx.x;
    if (e < N_EDGES) {
        const int d = ei[N_EDGES + e];
        const int pos = rowptr[d] + atomicAdd(&cursor[d], 1);
        esrc[pos] = ei[e];
    }
}

// ================= fp32 GEMM: C[M,128] = A[M,128] @ W[128,128] =================
__global__ __launch_bounds__(256) void k_gemm(const float* __restrict__ A,
                                              const float* __restrict__ W,
                                              float* __restrict__ C, int M) {
    __shared__ float sA[32][132];
    const int tid = threadIdx.x;
    const int tx = tid & 15;
    const int ty = tid >> 4;
    const int row0 = blockIdx.x * 128;

    float acc[8][8];
#pragma unroll
    for (int i = 0; i < 8; ++i)
#pragma unroll
        for (int j = 0; j < 8; ++j) acc[i][j] = 0.0f;

    for (int k0 = 0; k0 < 128; k0 += 32) {
        const int q = tid & 7;
        const int rb = tid >> 3;
#pragma unroll
        for (int it = 0; it < 4; ++it) {
            const int r = rb + 32 * it;
            const int grow = row0 + r;
            float4 v = {0.f, 0.f, 0.f, 0.f};
            if (grow < M) v = *(const float4*)(A + (size_t)grow * HID + k0 + 4 * q);
            sA[4 * q + 0][r] = v.x;
            sA[4 * q + 1][r] = v.y;
            sA[4 * q + 2][r] = v.z;
            sA[4 * q + 3][r] = v.w;
        }
        __syncthreads();

#pragma unroll 8
        for (int kk = 0; kk < 32; ++kk) {
            const float4 a0 = *(const float4*)&sA[kk][ty * 8];
            const float4 a1 = *(const float4*)&sA[kk][ty * 8 + 4];
            const float4 w0 = *(const float4*)(W + (size_t)(k0 + kk) * HID + tx * 8);
            const float4 w1 = *(const float4*)(W + (size_t)(k0 + kk) * HID + tx * 8 + 4);
            const float a[8] = {a0.x, a0.y, a0.z, a0.w, a1.x, a1.y, a1.z, a1.w};
            const float w[8] = {w0.x, w0.y, w0.z, w0.w, w1.x, w1.y, w1.z, w1.w};
#pragma unroll
            for (int i = 0; i < 8; ++i)
#pragma unroll
                for (int j = 0; j < 8; ++j)
                    acc[i][j] = fmaf(a[i], w[j], acc[i][j]);
        }
        __syncthreads();
    }

#pragma unroll
    for (int i = 0; i < 8; ++i) {
        const int row = row0 + ty * 8 + i;
        if (row < M) {
            float4 o0 = {acc[i][0], acc[i][1], acc[i][2], acc[i][3]};
            float4 o1 = {acc[i][4], acc[i][5], acc[i][6], acc[i][7]};
            *(float4*)(C + (size_t)row * HID + tx * 8) = o0;
            *(float4*)(C + (size_t)row * HID + tx * 8 + 4) = o1;
        }
    }
}

// ========== fused CSR gather-aggregate + self-term + bias + LayerNorm + ReLU ==========
// one wave per dst row; lane handles features {2*lane, 2*lane+1} as float2
__global__ __launch_bounds__(256) void k_agg_ln(const int* __restrict__ rowptr,
                                                const int* __restrict__ esrc,
                                                const float* __restrict__ h,
                                                const float* __restrict__ dinv,
                                                const float* __restrict__ b,
                                                const float* __restrict__ g,
                                                const float* __restrict__ be,
                                                float* __restrict__ out) {
    const int row = blockIdx.x * 4 + (threadIdx.x >> 6);
    const int lane = threadIdx.x & 63;
    if (row >= N_NODES) return;

    const int e0 = rowptr[row];
    const int e1 = rowptr[row + 1];

    float2 a0 = {0.f, 0.f}, a1 = {0.f, 0.f};
    int e = e0;
    for (; e + 1 < e1; e += 2) {
        const int s0 = esrc[e];
        const int s1 = esrc[e + 1];
        const float w0 = dinv[s0];
        const float w1 = dinv[s1];
        const float2 v0 = *(const float2*)(h + (size_t)s0 * HID + 2 * lane);
        const float2 v1 = *(const float2*)(h + (size_t)s1 * HID + 2 * lane);
        a0.x = fmaf(w0, v0.x, a0.x);
        a0.y = fmaf(w0, v0.y, a0.y);
        a1.x = fmaf(w1, v1.x, a1.x);
        a1.y = fmaf(w1, v1.y, a1.y);
    }
    if (e < e1) {
        const int s0 = esrc[e];
        const float w0 = dinv[s0];
        const float2 v0 = *(const float2*)(h + (size_t)s0 * HID + 2 * lane);
        a0.x = fmaf(w0, v0.x, a0.x);
        a0.y = fmaf(w0, v0.y, a0.y);
    }

    const float dd = dinv[row];
    const float sn = dd * dd;
    const float2 hv = *(const float2*)(h + (size_t)row * HID + 2 * lane);
    const float2 bb = *(const float2*)(b + 2 * lane);

    // agg*dinv[dst] + h*self_norm + bias
    float v0 = dd * (a0.x + a1.x) + hv.x * sn + bb.x;
    float v1 = dd * (a0.y + a1.y) + hv.y * sn + bb.y;

    float s = v0 + v1;
    float ss = v0 * v0 + v1 * v1;
#pragma unroll
    for (int off = 32; off > 0; off >>= 1) {
        s  += __shfl_down(s, off);
        ss += __shfl_down(ss, off);
    }
    s  = __shfl(s, 0);
    ss = __shfl(ss, 0);

    const float mu = s * (1.0f / 128.0f);
    const float var = ss * (1.0f / 128.0f) - mu * mu;
    const float rs = rsqrtf(var + LN_EPS);

    const float2 gg = *(const float2*)(g + 2 * lane);
    const float2 ee = *(const float2*)(be + 2 * lane);
    float2 o;
    o.x = fmaxf((v0 - mu) * rs * gg.x + ee.x, 0.0f);
    o.y = fmaxf((v1 - mu) * rs * gg.y + ee.y, 0.0f);
    *(float2*)(out + (size_t)row * HID + 2 * lane) = o;
}

// ================= launch =================
extern "C" void kernel_launch(void* const* d_in, const int* in_sizes, int n_in,
                              void* d_out, int out_size, void* d_ws, size_t ws_size,
                              hipStream_t stream) {
    (void)in_sizes; (void)n_in; (void)out_size; (void)ws_size;

    const float* x   = (const float*)d_in[0];
    const int*   ei  = (const int*)d_in[1];     // [2,E]: src = ei[e], dst = ei[E+e]
    const float* W1  = (const float*)d_in[2];
    const float* b1  = (const float*)d_in[3];
    const float* g1  = (const float*)d_in[4];
    const float* be1 = (const float*)d_in[5];
    const float* W2  = (const float*)d_in[6];
    const float* b2  = (const float*)d_in[7];
    const float* g2  = (const float*)d_in[8];
    const float* be2 = (const float*)d_in[9];
    float* out = (float*)d_out;

    // workspace layout
    int* counts = (int*)d_ws;                    // 50000
    int* cursor = counts + N_NODES;              // 50000
    int* rowptr = cursor + N_NODES;              // 50001
    int* esrc   = rowptr + (N_NODES + 1);        // 600000
    float* dinv = (float*)(esrc + N_EDGES);      // 50000
    // 800001 ints so far; pad to 16B boundary (800004)
    float* h = (float*)d_ws + 800004;            // 6,400,000 floats

    const int nb_nodes = (N_NODES + 255) / 256;
    const int nb_edges = (N_EDGES + 255) / 256;
    const int nb_gemm  = (N_NODES + 127) / 128;
    const int nb_agg   = (N_NODES + 3) / 4;

    // ---- CSR build ----
    hipMemsetAsync(counts, 0, 2 * N_NODES * sizeof(int), stream);   // counts + cursor
    k_hist<<<nb_edges, 256, 0, stream>>>(ei, counts);
    k_scan<<<1, 1024, 0, stream>>>(counts, rowptr);
    k_dinv<<<nb_nodes, 256, 0, stream>>>(counts, dinv);
    k_place<<<nb_edges, 256, 0, stream>>>(ei, rowptr, cursor, esrc);

    // ---- layer 1 ----
    k_gemm<<<nb_gemm, 256, 0, stream>>>(x, W1, h, N_NODES);
    k_agg_ln<<<nb_agg, 256, 0, stream>>>(rowptr, esrc, h, dinv, b1, g1, be1, out);

    // ---- layer 2 ----
    k_gemm<<<nb_gemm, 256, 0, stream>>>(out, W2, h, N_NODES);
    k_agg_ln<<<nb_agg, 256, 0, stream>>>(rowptr, esrc, h, dinv, b2, g2, be2, out);
}

// Round 3
// 387.793 us; speedup vs baseline: 2.0102x; 1.2615x over previous
//
#include <hip/hip_runtime.h>

#define N_NODES 50000
#define N_EDGES 600000
#define HID 128
#define LN_EPS 1e-5f
#define NBLK_SCAN 196   // ceil(50000/256)

// ================= CSR build =================

// counts[dst]++ for every edge
__global__ __launch_bounds__(256) void k_hist(const int* __restrict__ ei, int* __restrict__ counts) {
    int e = blockIdx.x * 256 + threadIdx.x;
    if (e < N_EDGES) atomicAdd(&counts[ei[N_EDGES + e]], 1);
}

// phase A: per-block sums of counts -> bsum[block]
__global__ __launch_bounds__(256) void k_reduce(const int* __restrict__ counts, int* __restrict__ bsum) {
    __shared__ int s[256];
    const int tid = threadIdx.x;
    const int idx = blockIdx.x * 256 + tid;
    s[tid] = (idx < N_NODES) ? counts[idx] : 0;
    __syncthreads();
    for (int off = 128; off > 0; off >>= 1) {
        if (tid < off) s[tid] += s[tid + off];
        __syncthreads();
    }
    if (tid == 0) bsum[blockIdx.x] = s[0];
}

// phase B: exclusive scan of the 196 block sums -> boff; total -> rowptr[N]
__global__ __launch_bounds__(256) void k_scan_part(const int* __restrict__ bsum,
                                                   int* __restrict__ boff,
                                                   int* __restrict__ rowptr) {
    __shared__ int s[256];
    const int tid = threadIdx.x;
    const int v0 = (tid < NBLK_SCAN) ? bsum[tid] : 0;
    s[tid] = v0;
    __syncthreads();
    for (int off = 1; off < 256; off <<= 1) {
        int v = (tid >= off) ? s[tid - off] : 0;
        __syncthreads();
        s[tid] += v;
        __syncthreads();
    }
    if (tid < NBLK_SCAN) boff[tid] = s[tid] - v0;       // exclusive
    if (tid == 255) rowptr[N_NODES] = s[255];           // total
}

// phase C: per-block exclusive scan + block offset -> rowptr; fused dinv = rsqrt(deg+1)
__global__ __launch_bounds__(256) void k_scan_write(const int* __restrict__ counts,
                                                    const int* __restrict__ boff,
                                                    int* __restrict__ rowptr,
                                                    float* __restrict__ dinv) {
    __shared__ int s[256];
    const int tid = threadIdx.x;
    const int idx = blockIdx.x * 256 + tid;
    const int c = (idx < N_NODES) ? counts[idx] : 0;
    s[tid] = c;
    __syncthreads();
    for (int off = 1; off < 256; off <<= 1) {
        int v = (tid >= off) ? s[tid - off] : 0;
        __syncthreads();
        s[tid] += v;
        __syncthreads();
    }
    if (idx < N_NODES) {
        rowptr[idx] = boff[blockIdx.x] + s[tid] - c;    // exclusive
        dinv[idx] = rsqrtf((float)c + 1.0f);
    }
}

// scatter edge sources into CSR slots
__global__ __launch_bounds__(256) void k_place(const int* __restrict__ ei,
                                               const int* __restrict__ rowptr,
                                               int* __restrict__ cursor,
                                               int* __restrict__ esrc) {
    int e = blockIdx.x * 256 + threadIdx.x;
    if (e < N_EDGES) {
        const int d = ei[N_EDGES + e];
        const int pos = rowptr[d] + atomicAdd(&cursor[d], 1);
        esrc[pos] = ei[e];
    }
}

// ================= fp32 GEMM: C[M,128] = A[M,128] @ W[128,128] =================
__global__ __launch_bounds__(256) void k_gemm(const float* __restrict__ A,
                                              const float* __restrict__ W,
                                              float* __restrict__ C, int M) {
    __shared__ float sA[32][132];
    const int tid = threadIdx.x;
    const int tx = tid & 15;
    const int ty = tid >> 4;
    const int row0 = blockIdx.x * 128;

    float acc[8][8];
#pragma unroll
    for (int i = 0; i < 8; ++i)
#pragma unroll
        for (int j = 0; j < 8; ++j) acc[i][j] = 0.0f;

    for (int k0 = 0; k0 < 128; k0 += 32) {
        const int q = tid & 7;
        const int rb = tid >> 3;
#pragma unroll
        for (int it = 0; it < 4; ++it) {
            const int r = rb + 32 * it;
            const int grow = row0 + r;
            float4 v = {0.f, 0.f, 0.f, 0.f};
            if (grow < M) v = *(const float4*)(A + (size_t)grow * HID + k0 + 4 * q);
            sA[4 * q + 0][r] = v.x;
            sA[4 * q + 1][r] = v.y;
            sA[4 * q + 2][r] = v.z;
            sA[4 * q + 3][r] = v.w;
        }
        __syncthreads();

#pragma unroll 8
        for (int kk = 0; kk < 32; ++kk) {
            const float4 a0 = *(const float4*)&sA[kk][ty * 8];
            const float4 a1 = *(const float4*)&sA[kk][ty * 8 + 4];
            const float4 w0 = *(const float4*)(W + (size_t)(k0 + kk) * HID + tx * 8);
            const float4 w1 = *(const float4*)(W + (size_t)(k0 + kk) * HID + tx * 8 + 4);
            const float a[8] = {a0.x, a0.y, a0.z, a0.w, a1.x, a1.y, a1.z, a1.w};
            const float w[8] = {w0.x, w0.y, w0.z, w0.w, w1.x, w1.y, w1.z, w1.w};
#pragma unroll
            for (int i = 0; i < 8; ++i)
#pragma unroll
                for (int j = 0; j < 8; ++j)
                    acc[i][j] = fmaf(a[i], w[j], acc[i][j]);
        }
        __syncthreads();
    }

#pragma unroll
    for (int i = 0; i < 8; ++i) {
        const int row = row0 + ty * 8 + i;
        if (row < M) {
            float4 o0 = {acc[i][0], acc[i][1], acc[i][2], acc[i][3]};
            float4 o1 = {acc[i][4], acc[i][5], acc[i][6], acc[i][7]};
            *(float4*)(C + (size_t)row * HID + tx * 8) = o0;
            *(float4*)(C + (size_t)row * HID + tx * 8 + 4) = o1;
        }
    }
}

// ========== fused CSR gather-aggregate + self-term + bias + LayerNorm + ReLU ==========
// one wave per dst row; lane handles features {2*lane, 2*lane+1} as float2
__global__ __launch_bounds__(256) void k_agg_ln(const int* __restrict__ rowptr,
                                                const int* __restrict__ esrc,
                                                const float* __restrict__ h,
                                                const float* __restrict__ dinv,
                                                const float* __restrict__ b,
                                                const float* __restrict__ g,
                                                const float* __restrict__ be,
                                                float* __restrict__ out) {
    const int row = blockIdx.x * 4 + (threadIdx.x >> 6);
    const int lane = threadIdx.x & 63;
    if (row >= N_NODES) return;

    const int e0 = rowptr[row];
    const int e1 = rowptr[row + 1];

    float2 a0 = {0.f, 0.f}, a1 = {0.f, 0.f};
    int e = e0;
    for (; e + 1 < e1; e += 2) {
        const int s0 = esrc[e];
        const int s1 = esrc[e + 1];
        const float w0 = dinv[s0];
        const float w1 = dinv[s1];
        const float2 v0 = *(const float2*)(h + (size_t)s0 * HID + 2 * lane);
        const float2 v1 = *(const float2*)(h + (size_t)s1 * HID + 2 * lane);
        a0.x = fmaf(w0, v0.x, a0.x);
        a0.y = fmaf(w0, v0.y, a0.y);
        a1.x = fmaf(w1, v1.x, a1.x);
        a1.y = fmaf(w1, v1.y, a1.y);
    }
    if (e < e1) {
        const int s0 = esrc[e];
        const float w0 = dinv[s0];
        const float2 v0 = *(const float2*)(h + (size_t)s0 * HID + 2 * lane);
        a0.x = fmaf(w0, v0.x, a0.x);
        a0.y = fmaf(w0, v0.y, a0.y);
    }

    const float dd = dinv[row];
    const float sn = dd * dd;
    const float2 hv = *(const float2*)(h + (size_t)row * HID + 2 * lane);
    const float2 bb = *(const float2*)(b + 2 * lane);

    float v0 = dd * (a0.x + a1.x) + hv.x * sn + bb.x;
    float v1 = dd * (a0.y + a1.y) + hv.y * sn + bb.y;

    float s = v0 + v1;
    float ss = v0 * v0 + v1 * v1;
#pragma unroll
    for (int off = 32; off > 0; off >>= 1) {
        s  += __shfl_down(s, off);
        ss += __shfl_down(ss, off);
    }
    s  = __shfl(s, 0);
    ss = __shfl(ss, 0);

    const float mu = s * (1.0f / 128.0f);
    const float var = ss * (1.0f / 128.0f) - mu * mu;
    const float rs = rsqrtf(var + LN_EPS);

    const float2 gg = *(const float2*)(g + 2 * lane);
    const float2 ee = *(const float2*)(be + 2 * lane);
    float2 o;
    o.x = fmaxf((v0 - mu) * rs * gg.x + ee.x, 0.0f);
    o.y = fmaxf((v1 - mu) * rs * gg.y + ee.y, 0.0f);
    *(float2*)(out + (size_t)row * HID + 2 * lane) = o;
}

// ================= launch =================
extern "C" void kernel_launch(void* const* d_in, const int* in_sizes, int n_in,
                              void* d_out, int out_size, void* d_ws, size_t ws_size,
                              hipStream_t stream) {
    (void)in_sizes; (void)n_in; (void)out_size; (void)ws_size;

    const float* x   = (const float*)d_in[0];
    const int*   ei  = (const int*)d_in[1];     // [2,E]: src = ei[e], dst = ei[E+e]
    const float* W1  = (const float*)d_in[2];
    const float* b1  = (const float*)d_in[3];
    const float* g1  = (const float*)d_in[4];
    const float* be1 = (const float*)d_in[5];
    const float* W2  = (const float*)d_in[6];
    const float* b2  = (const float*)d_in[7];
    const float* g2  = (const float*)d_in[8];
    const float* be2 = (const float*)d_in[9];
    float* out = (float*)d_out;

    // workspace layout (int/float elements)
    int* counts = (int*)d_ws;                    // [0, 50000)
    int* cursor = counts + N_NODES;              // [50000, 100000)
    int* rowptr = cursor + N_NODES;              // [100000, 150001)
    int* bsum   = (int*)d_ws + 150016;           // [150016, 150272)
    int* boff   = (int*)d_ws + 150272;           // [150272, 150528)
    int* esrc   = (int*)d_ws + 150528;           // [150528, 750528)
    float* dinv = (float*)d_ws + 750528;         // [750528, 800528)
    float* h    = (float*)d_ws + 800544;         // 6.4M floats, 16B-aligned

    const int nb_edges = (N_EDGES + 255) / 256;
    const int nb_gemm  = (N_NODES + 127) / 128;
    const int nb_agg   = (N_NODES + 3) / 4;

    // ---- CSR build ----
    hipMemsetAsync(counts, 0, 2 * N_NODES * sizeof(int), stream);   // counts + cursor
    k_hist<<<nb_edges, 256, 0, stream>>>(ei, counts);
    k_reduce<<<NBLK_SCAN, 256, 0, stream>>>(counts, bsum);
    k_scan_part<<<1, 256, 0, stream>>>(bsum, boff, rowptr);
    k_scan_write<<<NBLK_SCAN, 256, 0, stream>>>(counts, boff, rowptr, dinv);
    k_place<<<nb_edges, 256, 0, stream>>>(ei, rowptr, cursor, esrc);

    // ---- layer 1 ----
    k_gemm<<<nb_gemm, 256, 0, stream>>>(x, W1, h, N_NODES);
    k_agg_ln<<<nb_agg, 256, 0, stream>>>(rowptr, esrc, h, dinv, b1, g1, be1, out);

    // ---- layer 2 ----
    k_gemm<<<nb_gemm, 256, 0, stream>>>(out, W2, h, N_NODES);
    k_agg_ln<<<nb_agg, 256, 0, stream>>>(rowptr, esrc, h, dinv, b2, g2, be2, out);
}

// Round 4
// 297.617 us; speedup vs baseline: 2.6192x; 1.3030x over previous
//
#include <hip/hip_runtime.h>

#define N_NODES 50000
#define N_EDGES 600000
#define HID 128
#define LN_EPS 1e-5f
#define NBLK_SCAN 196   // ceil(50000/256)

typedef __attribute__((ext_vector_type(8))) short short8;
typedef __attribute__((ext_vector_type(4))) float f32x4;

__device__ inline float b2f(unsigned short u) {
    union { unsigned int i; float f; } v;
    v.i = ((unsigned int)u) << 16;
    return v.f;
}
__device__ inline unsigned short f2b(float f) {   // round-to-nearest-even
    union { float f; unsigned int u; } v; v.f = f;
    unsigned int r = (v.u + 0x7FFFu + ((v.u >> 16) & 1u)) >> 16;
    return (unsigned short)r;
}

// ================= CSR build =================

__global__ __launch_bounds__(256) void k_hist(const int* __restrict__ ei, int* __restrict__ counts) {
    int e = blockIdx.x * 256 + threadIdx.x;
    if (e < N_EDGES) atomicAdd(&counts[ei[N_EDGES + e]], 1);
}

__global__ __launch_bounds__(256) void k_reduce(const int* __restrict__ counts, int* __restrict__ bsum) {
    __shared__ int s[256];
    const int tid = threadIdx.x;
    const int idx = blockIdx.x * 256 + tid;
    s[tid] = (idx < N_NODES) ? counts[idx] : 0;
    __syncthreads();
    for (int off = 128; off > 0; off >>= 1) {
        if (tid < off) s[tid] += s[tid + off];
        __syncthreads();
    }
    if (tid == 0) bsum[blockIdx.x] = s[0];
}

__global__ __launch_bounds__(256) void k_scan_part(const int* __restrict__ bsum,
                                                   int* __restrict__ boff,
                                                   int* __restrict__ rowptr) {
    __shared__ int s[256];
    const int tid = threadIdx.x;
    const int v0 = (tid < NBLK_SCAN) ? bsum[tid] : 0;
    s[tid] = v0;
    __syncthreads();
    for (int off = 1; off < 256; off <<= 1) {
        int v = (tid >= off) ? s[tid - off] : 0;
        __syncthreads();
        s[tid] += v;
        __syncthreads();
    }
    if (tid < NBLK_SCAN) boff[tid] = s[tid] - v0;
    if (tid == 255) rowptr[N_NODES] = s[255];
}

__global__ __launch_bounds__(256) void k_scan_write(const int* __restrict__ counts,
                                                    const int* __restrict__ boff,
                                                    int* __restrict__ rowptr,
                                                    float* __restrict__ dinv) {
    __shared__ int s[256];
    const int tid = threadIdx.x;
    const int idx = blockIdx.x * 256 + tid;
    const int c = (idx < N_NODES) ? counts[idx] : 0;
    s[tid] = c;
    __syncthreads();
    for (int off = 1; off < 256; off <<= 1) {
        int v = (tid >= off) ? s[tid - off] : 0;
        __syncthreads();
        s[tid] += v;
        __syncthreads();
    }
    if (idx < N_NODES) {
        rowptr[idx] = boff[blockIdx.x] + s[tid] - c;
        dinv[idx] = rsqrtf((float)c + 1.0f);
    }
}

__global__ __launch_bounds__(256) void k_place(const int* __restrict__ ei,
                                               const int* __restrict__ rowptr,
                                               int* __restrict__ cursor,
                                               int* __restrict__ esrc) {
    int e = blockIdx.x * 256 + threadIdx.x;
    if (e < N_EDGES) {
        const int d = ei[N_EDGES + e];
        const int pos = rowptr[d] + atomicAdd(&cursor[d], 1);
        esrc[pos] = ei[e];
    }
}

// ================= conversions =================

// x fp32 -> bf16, 4 elems/thread
__global__ __launch_bounds__(256) void k_convert(const float* __restrict__ x, unsigned short* __restrict__ xb) {
    const long i = ((long)blockIdx.x * 256 + threadIdx.x) * 4;
    if (i < (long)N_NODES * HID) {
        const float4 v = *(const float4*)(x + i);
        unsigned short o[4] = {f2b(v.x), f2b(v.y), f2b(v.z), f2b(v.w)};
        *(ushort2*)(xb + i)     = make_ushort2(o[0], o[1]);
        *(ushort2*)(xb + i + 2) = make_ushort2(o[2], o[3]);
    }
}

// W[128][128] fp32 -> WT[128][128] bf16 (transposed)
__global__ __launch_bounds__(256) void k_wt(const float* __restrict__ W, unsigned short* __restrict__ WT) {
    const int i = blockIdx.x * 256 + threadIdx.x;   // 64 blocks
    const int k = i >> 7, n = i & 127;
    WT[n * 128 + k] = f2b(W[i]);
}

// ================= MFMA GEMM: hb[M,128](bf16) = Ab[M,128](bf16) @ WT^T =================
// block = 4 waves x 16 rows = 64 rows; no LDS; WT is L2-resident.
__global__ __launch_bounds__(256) void k_gemm(const unsigned short* __restrict__ Ab,
                                              const unsigned short* __restrict__ WT,
                                              unsigned short* __restrict__ hb, int M) {
    const int tid  = threadIdx.x;
    const int lane = tid & 63;
    const int ln   = lane & 15;          // row (A) / col (B,C)
    const int quad = lane >> 4;          // 0..3
    const int m0   = blockIdx.x * 64 + (tid >> 6) * 16;

    f32x4 acc[8];
#pragma unroll
    for (int t = 0; t < 8; ++t) acc[t] = (f32x4){0.f, 0.f, 0.f, 0.f};

    int arow = m0 + ln;
    if (arow >= M) arow = M - 1;         // clamp (stores are guarded)
    const unsigned short* aptr = Ab + (size_t)arow * HID + quad * 8;
    const unsigned short* bptr = WT + (size_t)ln * HID + quad * 8;

#pragma unroll
    for (int ks = 0; ks < 4; ++ks) {
        const short8 a = *(const short8*)(aptr + ks * 32);
#pragma unroll
        for (int t = 0; t < 8; ++t) {
            const short8 b = *(const short8*)(bptr + (size_t)t * 16 * HID + ks * 32);
            acc[t] = __builtin_amdgcn_mfma_f32_16x16x32_bf16(a, b, acc[t], 0, 0, 0);
        }
    }

#pragma unroll
    for (int t = 0; t < 8; ++t) {
#pragma unroll
        for (int r = 0; r < 4; ++r) {
            const int row = m0 + quad * 4 + r;
            if (row < M) hb[(size_t)row * HID + t * 16 + ln] = f2b(acc[t][r]);
        }
    }
}

// ====== fused CSR gather-aggregate + self-term + bias + LayerNorm + ReLU (bf16 h) ======
// one wave per dst row; lane handles features {2*lane, 2*lane+1}
__global__ __launch_bounds__(256) void k_agg_ln(const int* __restrict__ rowptr,
                                                const int* __restrict__ esrc,
                                                const unsigned short* __restrict__ h,
                                                const float* __restrict__ dinv,
                                                const float* __restrict__ b,
                                                const float* __restrict__ g,
                                                const float* __restrict__ be,
                                                float* __restrict__ outf,          // may be null
                                                unsigned short* __restrict__ outb) // may be null
{
    const int row = blockIdx.x * 4 + (threadIdx.x >> 6);
    const int lane = threadIdx.x & 63;
    if (row >= N_NODES) return;

    const int e0 = rowptr[row];
    const int e1 = rowptr[row + 1];

    float ax0 = 0.f, ay0 = 0.f, ax1 = 0.f, ay1 = 0.f;
    int e = e0;
    for (; e + 1 < e1; e += 2) {
        const int s0 = esrc[e];
        const int s1 = esrc[e + 1];
        const float w0 = dinv[s0];
        const float w1 = dinv[s1];
        const ushort2 v0 = *(const ushort2*)(h + (size_t)s0 * HID + 2 * lane);
        const ushort2 v1 = *(const ushort2*)(h + (size_t)s1 * HID + 2 * lane);
        ax0 = fmaf(w0, b2f(v0.x), ax0);
        ay0 = fmaf(w0, b2f(v0.y), ay0);
        ax1 = fmaf(w1, b2f(v1.x), ax1);
        ay1 = fmaf(w1, b2f(v1.y), ay1);
    }
    if (e < e1) {
        const int s0 = esrc[e];
        const float w0 = dinv[s0];
        const ushort2 v0 = *(const ushort2*)(h + (size_t)s0 * HID + 2 * lane);
        ax0 = fmaf(w0, b2f(v0.x), ax0);
        ay0 = fmaf(w0, b2f(v0.y), ay0);
    }

    const float dd = dinv[row];
    const float sn = dd * dd;
    const ushort2 hv = *(const ushort2*)(h + (size_t)row * HID + 2 * lane);
    const float2 bb = *(const float2*)(b + 2 * lane);

    float v0 = dd * (ax0 + ax1) + b2f(hv.x) * sn + bb.x;
    float v1 = dd * (ay0 + ay1) + b2f(hv.y) * sn + bb.y;

    float s = v0 + v1;
    float ss = v0 * v0 + v1 * v1;
#pragma unroll
    for (int off = 32; off > 0; off >>= 1) {
        s  += __shfl_down(s, off);
        ss += __shfl_down(ss, off);
    }
    s  = __shfl(s, 0);
    ss = __shfl(ss, 0);

    const float mu = s * (1.0f / 128.0f);
    const float var = ss * (1.0f / 128.0f) - mu * mu;
    const float rs = rsqrtf(var + LN_EPS);

    const float2 gg = *(const float2*)(g + 2 * lane);
    const float2 ee = *(const float2*)(be + 2 * lane);
    const float o0 = fmaxf((v0 - mu) * rs * gg.x + ee.x, 0.0f);
    const float o1 = fmaxf((v1 - mu) * rs * gg.y + ee.y, 0.0f);

    if (outf) {
        *(float2*)(outf + (size_t)row * HID + 2 * lane) = make_float2(o0, o1);
    }
    if (outb) {
        *(ushort2*)(outb + (size_t)row * HID + 2 * lane) = make_ushort2(f2b(o0), f2b(o1));
    }
}

// ================= launch =================
extern "C" void kernel_launch(void* const* d_in, const int* in_sizes, int n_in,
                              void* d_out, int out_size, void* d_ws, size_t ws_size,
                              hipStream_t stream) {
    (void)in_sizes; (void)n_in; (void)out_size; (void)ws_size;

    const float* x   = (const float*)d_in[0];
    const int*   ei  = (const int*)d_in[1];     // [2,E]: src = ei[e], dst = ei[E+e]
    const float* W1  = (const float*)d_in[2];
    const float* b1  = (const float*)d_in[3];
    const float* g1  = (const float*)d_in[4];
    const float* be1 = (const float*)d_in[5];
    const float* W2  = (const float*)d_in[6];
    const float* b2  = (const float*)d_in[7];
    const float* g2  = (const float*)d_in[8];
    const float* be2 = (const float*)d_in[9];
    float* out = (float*)d_out;

    // workspace layout (4-byte element offsets), total = 7,200,544 dwords (~28.8 MB)
    int* counts = (int*)d_ws;                              // [0, 50000)
    int* cursor = counts + N_NODES;                        // [50000, 100000)  (dead after k_place)
    unsigned short* WT = (unsigned short*)cursor;          // reuse: 16384 ushorts = 8192 dwords
    int* rowptr = (int*)d_ws + 100000;                     // [100000, 150001)
    int* bsum   = (int*)d_ws + 150016;
    int* boff   = (int*)d_ws + 150272;
    int* esrc   = (int*)d_ws + 150528;                     // [150528, 750528)
    float* dinv = (float*)d_ws + 750528;                   // [750528, 800528)
    unsigned short* xb = (unsigned short*)((int*)d_ws + 800544);   // 6.4M bf16 = 3.2M dwords
    unsigned short* hb = (unsigned short*)((int*)d_ws + 4000544);  // 6.4M bf16

    const int nb_edges = (N_EDGES + 255) / 256;
    const int nb_gemm  = (N_NODES + 63) / 64;              // 782
    const int nb_agg   = (N_NODES + 3) / 4;
    const int nb_conv  = (N_NODES * HID / 4 + 255) / 256;  // 6250

    // ---- CSR build ----
    hipMemsetAsync(counts, 0, 2 * N_NODES * sizeof(int), stream);
    k_hist<<<nb_edges, 256, 0, stream>>>(ei, counts);
    k_reduce<<<NBLK_SCAN, 256, 0, stream>>>(counts, bsum);
    k_scan_part<<<1, 256, 0, stream>>>(bsum, boff, rowptr);
    k_scan_write<<<NBLK_SCAN, 256, 0, stream>>>(counts, boff, rowptr, dinv);
    k_place<<<nb_edges, 256, 0, stream>>>(ei, rowptr, cursor, esrc);   // cursor use ends here

    // ---- x -> bf16 ----
    k_convert<<<nb_conv, 256, 0, stream>>>(x, xb);

    // ---- layer 1 ----
    k_wt<<<64, 256, 0, stream>>>(W1, WT);
    k_gemm<<<nb_gemm, 256, 0, stream>>>(xb, WT, hb, N_NODES);
    // y1 (bf16) -> xb (x no longer needed)
    k_agg_ln<<<nb_agg, 256, 0, stream>>>(rowptr, esrc, hb, dinv, b1, g1, be1, nullptr, xb);

    // ---- layer 2 ----
    k_wt<<<64, 256, 0, stream>>>(W2, WT);
    k_gemm<<<nb_gemm, 256, 0, stream>>>(xb, WT, hb, N_NODES);
    k_agg_ln<<<nb_agg, 256, 0, stream>>>(rowptr, esrc, hb, dinv, b2, g2, be2, out, nullptr);
}

// Round 5
// 272.511 us; speedup vs baseline: 2.8605x; 1.0921x over previous
//
#include <hip/hip_runtime.h>

#define N_NODES 50000
#define N_EDGES 600000
#define HID 128
#define LN_EPS 1e-5f
#define NBLK_SCAN 196   // ceil(50000/256)

typedef __attribute__((ext_vector_type(8))) short short8;
typedef __attribute__((ext_vector_type(4))) float f32x4;

__device__ inline float b2f(unsigned short u) {
    union { unsigned int i; float f; } v;
    v.i = ((unsigned int)u) << 16;
    return v.f;
}
__device__ inline unsigned short f2b(float f) {   // round-to-nearest-even
    union { float f; unsigned int u; } v; v.f = f;
    unsigned int r = (v.u + 0x7FFFu + ((v.u >> 16) & 1u)) >> 16;
    return (unsigned short)r;
}

// ================= CSR build =================

__global__ __launch_bounds__(256) void k_hist(const int* __restrict__ ei, int* __restrict__ counts) {
    int e = blockIdx.x * 256 + threadIdx.x;
    if (e < N_EDGES) atomicAdd(&counts[ei[N_EDGES + e]], 1);
}

__global__ __launch_bounds__(256) void k_reduce(const int* __restrict__ counts, int* __restrict__ bsum) {
    __shared__ int s[256];
    const int tid = threadIdx.x;
    const int idx = blockIdx.x * 256 + tid;
    s[tid] = (idx < N_NODES) ? counts[idx] : 0;
    __syncthreads();
    for (int off = 128; off > 0; off >>= 1) {
        if (tid < off) s[tid] += s[tid + off];
        __syncthreads();
    }
    if (tid == 0) bsum[blockIdx.x] = s[0];
}

__global__ __launch_bounds__(256) void k_scan_part(const int* __restrict__ bsum,
                                                   int* __restrict__ boff,
                                                   int* __restrict__ rowptr) {
    __shared__ int s[256];
    const int tid = threadIdx.x;
    const int v0 = (tid < NBLK_SCAN) ? bsum[tid] : 0;
    s[tid] = v0;
    __syncthreads();
    for (int off = 1; off < 256; off <<= 1) {
        int v = (tid >= off) ? s[tid - off] : 0;
        __syncthreads();
        s[tid] += v;
        __syncthreads();
    }
    if (tid < NBLK_SCAN) boff[tid] = s[tid] - v0;
    if (tid == 255) rowptr[N_NODES] = s[255];
}

__global__ __launch_bounds__(256) void k_scan_write(const int* __restrict__ counts,
                                                    const int* __restrict__ boff,
                                                    int* __restrict__ rowptr,
                                                    float* __restrict__ dinv) {
    __shared__ int s[256];
    const int tid = threadIdx.x;
    const int idx = blockIdx.x * 256 + tid;
    const int c = (idx < N_NODES) ? counts[idx] : 0;
    s[tid] = c;
    __syncthreads();
    for (int off = 1; off < 256; off <<= 1) {
        int v = (tid >= off) ? s[tid - off] : 0;
        __syncthreads();
        s[tid] += v;
        __syncthreads();
    }
    if (idx < N_NODES) {
        rowptr[idx] = boff[blockIdx.x] + s[tid] - c;
        dinv[idx] = rsqrtf((float)c + 1.0f);
    }
}

__global__ __launch_bounds__(256) void k_place(const int* __restrict__ ei,
                                               const int* __restrict__ rowptr,
                                               int* __restrict__ cursor,
                                               int* __restrict__ esrc) {
    int e = blockIdx.x * 256 + threadIdx.x;
    if (e < N_EDGES) {
        const int d = ei[N_EDGES + e];
        const int pos = rowptr[d] + atomicAdd(&cursor[d], 1);
        esrc[pos] = ei[e];
    }
}

// W[128][128] fp32 -> WT[128][128] bf16 (transposed)
__global__ __launch_bounds__(256) void k_wt(const float* __restrict__ W, unsigned short* __restrict__ WT) {
    const int i = blockIdx.x * 256 + threadIdx.x;   // 64 blocks
    const int k = i >> 7, n = i & 127;
    WT[n * 128 + k] = f2b(W[i]);
}

// ================= MFMA GEMM: hb[M,128](bf16) = A[M,128] @ WT^T =================
// block = 4 waves x 16 rows = 64 rows; no LDS; WT is L2-resident.
// A loader templated: fp32 (layer 1, converts in-register) or bf16.
__device__ inline short8 load_a_frag(const unsigned short* p) {
    return *(const short8*)p;
}
__device__ inline short8 load_a_frag(const float* p) {
    const float4 v0 = *(const float4*)p;
    const float4 v1 = *(const float4*)(p + 4);
    short8 r;
    r[0] = (short)f2b(v0.x); r[1] = (short)f2b(v0.y);
    r[2] = (short)f2b(v0.z); r[3] = (short)f2b(v0.w);
    r[4] = (short)f2b(v1.x); r[5] = (short)f2b(v1.y);
    r[6] = (short)f2b(v1.z); r[7] = (short)f2b(v1.w);
    return r;
}

template <typename TA>
__global__ __launch_bounds__(256) void k_gemm(const TA* __restrict__ A,
                                              const unsigned short* __restrict__ WT,
                                              unsigned short* __restrict__ hb, int M) {
    const int tid  = threadIdx.x;
    const int lane = tid & 63;
    const int ln   = lane & 15;          // row (A) / col (B,C)
    const int quad = lane >> 4;          // 0..3
    const int m0   = blockIdx.x * 64 + (tid >> 6) * 16;

    f32x4 acc[8];
#pragma unroll
    for (int t = 0; t < 8; ++t) acc[t] = (f32x4){0.f, 0.f, 0.f, 0.f};

    int arow = m0 + ln;
    if (arow >= M) arow = M - 1;         // clamp (stores are guarded)
    const TA* aptr = A + (size_t)arow * HID + quad * 8;
    const unsigned short* bptr = WT + (size_t)ln * HID + quad * 8;

#pragma unroll
    for (int ks = 0; ks < 4; ++ks) {
        const short8 a = load_a_frag(aptr + ks * 32);
#pragma unroll
        for (int t = 0; t < 8; ++t) {
            const short8 b = *(const short8*)(bptr + (size_t)t * 16 * HID + ks * 32);
            acc[t] = __builtin_amdgcn_mfma_f32_16x16x32_bf16(a, b, acc[t], 0, 0, 0);
        }
    }

#pragma unroll
    for (int t = 0; t < 8; ++t) {
#pragma unroll
        for (int r = 0; r < 4; ++r) {
            const int row = m0 + quad * 4 + r;
            if (row < M) hb[(size_t)row * HID + t * 16 + ln] = f2b(acc[t][r]);
        }
    }
}

// ====== fused CSR gather-aggregate + self-term + bias + LayerNorm + ReLU (bf16 h) ======
// one wave per dst row; wave = 4 edge-groups x 16 feature-lanes; lane owns 8 features (16B gathers)
__global__ __launch_bounds__(256) void k_agg_ln(const int* __restrict__ rowptr,
                                                const int* __restrict__ esrc,
                                                const unsigned short* __restrict__ h,
                                                const float* __restrict__ dinv,
                                                const float* __restrict__ b,
                                                const float* __restrict__ g,
                                                const float* __restrict__ be,
                                                float* __restrict__ outf,          // may be null
                                                unsigned short* __restrict__ outb) // may be null
{
    const int row  = blockIdx.x * 4 + (threadIdx.x >> 6);
    const int lane = threadIdx.x & 63;
    const int grp  = lane >> 4;      // 0..3: which edge of the 4-edge batch
    const int fl   = lane & 15;      // feature lane: owns features 8*fl .. 8*fl+7
    if (row >= N_NODES) return;

    const int e0 = rowptr[row];
    const int e1 = rowptr[row + 1];

    float acc[8];
#pragma unroll
    for (int j = 0; j < 8; ++j) acc[j] = 0.f;

    for (int e = e0 + grp; e < e1; e += 4) {
        const int s = esrc[e];                    // broadcast across 16 lanes of the group
        const float w = dinv[s];
        const short8 v = *(const short8*)(h + (size_t)s * HID + 8 * fl);
#pragma unroll
        for (int j = 0; j < 8; ++j)
            acc[j] = fmaf(w, b2f((unsigned short)v[j]), acc[j]);
    }

    // merge the 4 edge-groups (lanes l, l^16, l^32, l^48 own the same features)
#pragma unroll
    for (int j = 0; j < 8; ++j) {
        acc[j] += __shfl_xor(acc[j], 16);
        acc[j] += __shfl_xor(acc[j], 32);
    }

    const float dd = dinv[row];
    const float sn = dd * dd;
    const short8 hv = *(const short8*)(h + (size_t)row * HID + 8 * fl);
    const float4 b0 = *(const float4*)(b + 8 * fl);
    const float4 b1 = *(const float4*)(b + 8 * fl + 4);
    const float bb[8] = {b0.x, b0.y, b0.z, b0.w, b1.x, b1.y, b1.z, b1.w};

    float v[8], s = 0.f, ss = 0.f;
#pragma unroll
    for (int j = 0; j < 8; ++j) {
        v[j] = dd * acc[j] + b2f((unsigned short)hv[j]) * sn + bb[j];
        s += v[j];
        ss = fmaf(v[j], v[j], ss);
    }

    // LN stats: reduce across the 16 feature lanes (groups hold identical copies)
#pragma unroll
    for (int off = 1; off <= 8; off <<= 1) {
        s  += __shfl_xor(s, off);
        ss += __shfl_xor(ss, off);
    }

    const float mu = s * (1.0f / 128.0f);
    const float var = ss * (1.0f / 128.0f) - mu * mu;
    const float rs = rsqrtf(var + LN_EPS);

    if (grp == 0) {
        const float4 g0 = *(const float4*)(g + 8 * fl);
        const float4 g1 = *(const float4*)(g + 8 * fl + 4);
        const float4 e0v = *(const float4*)(be + 8 * fl);
        const float4 e1v = *(const float4*)(be + 8 * fl + 4);
        const float gg[8] = {g0.x, g0.y, g0.z, g0.w, g1.x, g1.y, g1.z, g1.w};
        const float ee[8] = {e0v.x, e0v.y, e0v.z, e0v.w, e1v.x, e1v.y, e1v.z, e1v.w};
        float o[8];
#pragma unroll
        for (int j = 0; j < 8; ++j)
            o[j] = fmaxf((v[j] - mu) * rs * gg[j] + ee[j], 0.0f);

        if (outf) {
            float4 w0 = {o[0], o[1], o[2], o[3]};
            float4 w1 = {o[4], o[5], o[6], o[7]};
            *(float4*)(outf + (size_t)row * HID + 8 * fl) = w0;
            *(float4*)(outf + (size_t)row * HID + 8 * fl + 4) = w1;
        }
        if (outb) {
            ushort4 w0 = {f2b(o[0]), f2b(o[1]), f2b(o[2]), f2b(o[3])};
            ushort4 w1 = {f2b(o[4]), f2b(o[5]), f2b(o[6]), f2b(o[7])};
            *(ushort4*)(outb + (size_t)row * HID + 8 * fl) = w0;
            *(ushort4*)(outb + (size_t)row * HID + 8 * fl + 4) = w1;
        }
    }
}

// ================= launch =================
extern "C" void kernel_launch(void* const* d_in, const int* in_sizes, int n_in,
                              void* d_out, int out_size, void* d_ws, size_t ws_size,
                              hipStream_t stream) {
    (void)in_sizes; (void)n_in; (void)out_size; (void)ws_size;

    const float* x   = (const float*)d_in[0];
    const int*   ei  = (const int*)d_in[1];     // [2,E]: src = ei[e], dst = ei[E+e]
    const float* W1  = (const float*)d_in[2];
    const float* b1  = (const float*)d_in[3];
    const float* g1  = (const float*)d_in[4];
    const float* be1 = (const float*)d_in[5];
    const float* W2  = (const float*)d_in[6];
    const float* b2  = (const float*)d_in[7];
    const float* g2  = (const float*)d_in[8];
    const float* be2 = (const float*)d_in[9];
    float* out = (float*)d_out;

    // workspace layout (4-byte element offsets)
    int* counts = (int*)d_ws;                              // [0, 50000)
    int* cursor = counts + N_NODES;                        // [50000, 100000)  (dead after k_place)
    unsigned short* WT = (unsigned short*)cursor;          // reuse: 16384 ushorts
    int* rowptr = (int*)d_ws + 100000;                     // [100000, 150001)
    int* bsum   = (int*)d_ws + 150016;
    int* boff   = (int*)d_ws + 150272;
    int* esrc   = (int*)d_ws + 150528;                     // [150528, 750528)
    float* dinv = (float*)d_ws + 750528;                   // [750528, 800528)
    unsigned short* yb = (unsigned short*)((int*)d_ws + 800544);   // layer-1 activations, bf16
    unsigned short* hb = (unsigned short*)((int*)d_ws + 4000544);  // GEMM output, bf16

    const int nb_edges = (N_EDGES + 255) / 256;
    const int nb_gemm  = (N_NODES + 63) / 64;              // 782
    const int nb_agg   = (N_NODES + 3) / 4;

    // ---- CSR build ----
    hipMemsetAsync(counts, 0, 2 * N_NODES * sizeof(int), stream);
    k_hist<<<nb_edges, 256, 0, stream>>>(ei, counts);
    k_reduce<<<NBLK_SCAN, 256, 0, stream>>>(counts, bsum);
    k_scan_part<<<1, 256, 0, stream>>>(bsum, boff, rowptr);
    k_scan_write<<<NBLK_SCAN, 256, 0, stream>>>(counts, boff, rowptr, dinv);
    k_place<<<nb_edges, 256, 0, stream>>>(ei, rowptr, cursor, esrc);   // cursor use ends here

    // ---- layer 1 (GEMM reads fp32 x directly, converts in-register) ----
    k_wt<<<64, 256, 0, stream>>>(W1, WT);
    k_gemm<float><<<nb_gemm, 256, 0, stream>>>(x, WT, hb, N_NODES);
    k_agg_ln<<<nb_agg, 256, 0, stream>>>(rowptr, esrc, hb, dinv, b1, g1, be1, nullptr, yb);

    // ---- layer 2 ----
    k_wt<<<64, 256, 0, stream>>>(W2, WT);
    k_gemm<unsigned short><<<nb_gemm, 256, 0, stream>>>(yb, WT, hb, N_NODES);
    k_agg_ln<<<nb_agg, 256, 0, stream>>>(rowptr, esrc, hb, dinv, b2, g2, be2, out, nullptr);
}

// Round 6
// 271.697 us; speedup vs baseline: 2.8691x; 1.0030x over previous
//
#include <hip/hip_runtime.h>

#define N_NODES 50000
#define N_EDGES 600000
#define HID 128
#define LN_EPS 1e-5f

typedef __attribute__((ext_vector_type(8))) short short8;
typedef __attribute__((ext_vector_type(4))) float f32x4;

__device__ inline float b2f(unsigned short u) {
    union { unsigned int i; float f; } v;
    v.i = ((unsigned int)u) << 16;
    return v.f;
}
__device__ inline unsigned short f2b(float f) {   // round-to-nearest-even
    union { float f; unsigned int u; } v; v.f = f;
    unsigned int r = (v.u + 0x7FFFu + ((v.u >> 16) & 1u)) >> 16;
    return (unsigned short)r;
}

// ================= CSR build =================

__global__ __launch_bounds__(256) void k_hist(const int* __restrict__ ei, int* __restrict__ counts) {
    int e = blockIdx.x * 256 + threadIdx.x;
    if (e < N_EDGES) atomicAdd(&counts[ei[N_EDGES + e]], 1);
}

// one kernel: slab-base assignment via per-wave scan + one atomic per wave; fused dinv
// slab[i] = start offset of row i's edge list (order arbitrary, rows contiguous)
__global__ __launch_bounds__(256) void k_slab(const int* __restrict__ counts,
                                              int* __restrict__ gtotal,
                                              int* __restrict__ slab,
                                              float* __restrict__ dinv) {
    const int idx  = blockIdx.x * 256 + threadIdx.x;
    const int lane = threadIdx.x & 63;
    const int c = (idx < N_NODES) ? counts[idx] : 0;

    // wave-inclusive scan of c
    int incl = c;
#pragma unroll
    for (int off = 1; off < 64; off <<= 1) {
        int n = __shfl_up(incl, off);
        if (lane >= off) incl += n;
    }
    const int wtot = __shfl(incl, 63);
    int base = 0;
    if (lane == 0) base = atomicAdd(gtotal, wtot);
    base = __shfl(base, 0);

    if (idx < N_NODES) {
        slab[idx] = base + incl - c;          // exclusive within wave + global base
        dinv[idx] = rsqrtf((float)c + 1.0f);
    }
}

// place edge sources; consumes slab (afterwards slab[d] == end of row d)
__global__ __launch_bounds__(256) void k_place(const int* __restrict__ ei,
                                               int* __restrict__ slab,
                                               int* __restrict__ esrc) {
    int e = blockIdx.x * 256 + threadIdx.x;
    if (e < N_EDGES) {
        const int d = ei[N_EDGES + e];
        const int pos = atomicAdd(&slab[d], 1);
        esrc[pos] = ei[e];
    }
}

// both weights fp32 -> bf16 transposed, one launch (128 blocks)
__global__ __launch_bounds__(256) void k_wt2(const float* __restrict__ W1, unsigned short* __restrict__ WT1,
                                             const float* __restrict__ W2, unsigned short* __restrict__ WT2) {
    const int i = blockIdx.x * 256 + threadIdx.x;
    if (i < 16384) {
        const int k = i >> 7, n = i & 127;
        WT1[n * 128 + k] = f2b(W1[i]);
    } else {
        const int j = i - 16384;
        const int k = j >> 7, n = j & 127;
        WT2[n * 128 + k] = f2b(W2[j]);
    }
}

// ================= MFMA GEMM: hb[M,128](bf16) = A[M,128] @ WT^T =================
__device__ inline short8 load_a_frag(const unsigned short* p) {
    return *(const short8*)p;
}
__device__ inline short8 load_a_frag(const float* p) {
    const float4 v0 = *(const float4*)p;
    const float4 v1 = *(const float4*)(p + 4);
    short8 r;
    r[0] = (short)f2b(v0.x); r[1] = (short)f2b(v0.y);
    r[2] = (short)f2b(v0.z); r[3] = (short)f2b(v0.w);
    r[4] = (short)f2b(v1.x); r[5] = (short)f2b(v1.y);
    r[6] = (short)f2b(v1.z); r[7] = (short)f2b(v1.w);
    return r;
}

template <typename TA>
__global__ __launch_bounds__(256) void k_gemm(const TA* __restrict__ A,
                                              const unsigned short* __restrict__ WT,
                                              unsigned short* __restrict__ hb, int M) {
    const int tid  = threadIdx.x;
    const int lane = tid & 63;
    const int ln   = lane & 15;
    const int quad = lane >> 4;
    const int m0   = blockIdx.x * 64 + (tid >> 6) * 16;

    f32x4 acc[8];
#pragma unroll
    for (int t = 0; t < 8; ++t) acc[t] = (f32x4){0.f, 0.f, 0.f, 0.f};

    int arow = m0 + ln;
    if (arow >= M) arow = M - 1;
    const TA* aptr = A + (size_t)arow * HID + quad * 8;
    const unsigned short* bptr = WT + (size_t)ln * HID + quad * 8;

#pragma unroll
    for (int ks = 0; ks < 4; ++ks) {
        const short8 a = load_a_frag(aptr + ks * 32);
#pragma unroll
        for (int t = 0; t < 8; ++t) {
            const short8 b = *(const short8*)(bptr + (size_t)t * 16 * HID + ks * 32);
            acc[t] = __builtin_amdgcn_mfma_f32_16x16x32_bf16(a, b, acc[t], 0, 0, 0);
        }
    }

#pragma unroll
    for (int t = 0; t < 8; ++t) {
#pragma unroll
        for (int r = 0; r < 4; ++r) {
            const int row = m0 + quad * 4 + r;
            if (row < M) hb[(size_t)row * HID + t * 16 + ln] = f2b(acc[t][r]);
        }
    }
}

// ====== fused CSR gather-aggregate + self-term + bias + LayerNorm + ReLU (bf16 h) ======
// wave per row: 4 edge-groups x 16 feature-lanes, unrolled x2 -> 8 gathers in flight
__global__ __launch_bounds__(256) void k_agg_ln(const int* __restrict__ slab_end,
                                                const int* __restrict__ counts,
                                                const int* __restrict__ esrc,
                                                const unsigned short* __restrict__ h,
                                                const float* __restrict__ dinv,
                                                const float* __restrict__ b,
                                                const float* __restrict__ g,
                                                const float* __restrict__ be,
                                                float* __restrict__ outf,          // may be null
                                                unsigned short* __restrict__ outb) // may be null
{
    const int row  = blockIdx.x * 4 + (threadIdx.x >> 6);
    const int lane = threadIdx.x & 63;
    const int grp  = lane >> 4;
    const int fl   = lane & 15;
    if (row >= N_NODES) return;

    const int e1 = slab_end[row];
    const int e0 = e1 - counts[row];

    float acc[8];
#pragma unroll
    for (int j = 0; j < 8; ++j) acc[j] = 0.f;

    int e = e0 + grp;
    for (; e + 4 < e1; e += 8) {
        const int sA = esrc[e];
        const int sB = esrc[e + 4];
        const float wA = dinv[sA];
        const float wB = dinv[sB];
        const short8 vA = *(const short8*)(h + (size_t)sA * HID + 8 * fl);
        const short8 vB = *(const short8*)(h + (size_t)sB * HID + 8 * fl);
#pragma unroll
        for (int j = 0; j < 8; ++j) {
            acc[j] = fmaf(wA, b2f((unsigned short)vA[j]), acc[j]);
            acc[j] = fmaf(wB, b2f((unsigned short)vB[j]), acc[j]);
        }
    }
    if (e < e1) {
        const int sA = esrc[e];
        const float wA = dinv[sA];
        const short8 vA = *(const short8*)(h + (size_t)sA * HID + 8 * fl);
#pragma unroll
        for (int j = 0; j < 8; ++j)
            acc[j] = fmaf(wA, b2f((unsigned short)vA[j]), acc[j]);
    }

    // merge the 4 edge-groups
#pragma unroll
    for (int j = 0; j < 8; ++j) {
        acc[j] += __shfl_xor(acc[j], 16);
        acc[j] += __shfl_xor(acc[j], 32);
    }

    const float dd = dinv[row];
    const float sn = dd * dd;
    const short8 hv = *(const short8*)(h + (size_t)row * HID + 8 * fl);
    const float4 b0 = *(const float4*)(b + 8 * fl);
    const float4 b1 = *(const float4*)(b + 8 * fl + 4);
    const float bb[8] = {b0.x, b0.y, b0.z, b0.w, b1.x, b1.y, b1.z, b1.w};

    float v[8], s = 0.f, ss = 0.f;
#pragma unroll
    for (int j = 0; j < 8; ++j) {
        v[j] = dd * acc[j] + b2f((unsigned short)hv[j]) * sn + bb[j];
        s += v[j];
        ss = fmaf(v[j], v[j], ss);
    }

    // LN stats across the 16 feature lanes
#pragma unroll
    for (int off = 1; off <= 8; off <<= 1) {
        s  += __shfl_xor(s, off);
        ss += __shfl_xor(ss, off);
    }

    const float mu = s * (1.0f / 128.0f);
    const float var = ss * (1.0f / 128.0f) - mu * mu;
    const float rs = rsqrtf(var + LN_EPS);

    if (grp == 0) {
        const float4 g0 = *(const float4*)(g + 8 * fl);
        const float4 g1 = *(const float4*)(g + 8 * fl + 4);
        const float4 e0v = *(const float4*)(be + 8 * fl);
        const float4 e1v = *(const float4*)(be + 8 * fl + 4);
        const float gg[8] = {g0.x, g0.y, g0.z, g0.w, g1.x, g1.y, g1.z, g1.w};
        const float ee[8] = {e0v.x, e0v.y, e0v.z, e0v.w, e1v.x, e1v.y, e1v.z, e1v.w};
        float o[8];
#pragma unroll
        for (int j = 0; j < 8; ++j)
            o[j] = fmaxf((v[j] - mu) * rs * gg[j] + ee[j], 0.0f);

        if (outf) {
            float4 w0 = {o[0], o[1], o[2], o[3]};
            float4 w1 = {o[4], o[5], o[6], o[7]};
            *(float4*)(outf + (size_t)row * HID + 8 * fl) = w0;
            *(float4*)(outf + (size_t)row * HID + 8 * fl + 4) = w1;
        }
        if (outb) {
            ushort4 w0 = {f2b(o[0]), f2b(o[1]), f2b(o[2]), f2b(o[3])};
            ushort4 w1 = {f2b(o[4]), f2b(o[5]), f2b(o[6]), f2b(o[7])};
            *(ushort4*)(outb + (size_t)row * HID + 8 * fl) = w0;
            *(ushort4*)(outb + (size_t)row * HID + 8 * fl + 4) = w1;
        }
    }
}

// ================= launch =================
extern "C" void kernel_launch(void* const* d_in, const int* in_sizes, int n_in,
                              void* d_out, int out_size, void* d_ws, size_t ws_size,
                              hipStream_t stream) {
    (void)in_sizes; (void)n_in; (void)out_size; (void)ws_size;

    const float* x   = (const float*)d_in[0];
    const int*   ei  = (const int*)d_in[1];     // [2,E]: src = ei[e], dst = ei[E+e]
    const float* W1  = (const float*)d_in[2];
    const float* b1  = (const float*)d_in[3];
    const float* g1  = (const float*)d_in[4];
    const float* be1 = (const float*)d_in[5];
    const float* W2  = (const float*)d_in[6];
    const float* b2  = (const float*)d_in[7];
    const float* g2  = (const float*)d_in[8];
    const float* be2 = (const float*)d_in[9];
    float* out = (float*)d_out;

    // workspace layout (dword offsets)
    int* counts = (int*)d_ws;                              // [0, 50000)
    int* gtotal = counts + N_NODES;                        // [50000]  (memset covers counts+gtotal)
    int* slab   = (int*)d_ws + 50016;                      // [50016, 100016)
    float* dinv = (float*)d_ws + 100016;                   // [100016, 150016)
    int* esrc   = (int*)d_ws + 150016;                     // [150016, 750016)
    unsigned short* WT1 = (unsigned short*)((int*)d_ws + 750016);  // 8192 dwords
    unsigned short* WT2 = (unsigned short*)((int*)d_ws + 758208);  // 8192 dwords
    unsigned short* hb  = (unsigned short*)((int*)d_ws + 766400);  // 3.2M dwords
    unsigned short* yb  = (unsigned short*)((int*)d_ws + 3966400); // 3.2M dwords

    const int nb_edges = (N_EDGES + 255) / 256;
    const int nb_nodes = (N_NODES + 255) / 256;
    const int nb_gemm  = (N_NODES + 63) / 64;
    const int nb_agg   = (N_NODES + 3) / 4;

    // ---- CSR build (4 dispatches + memset) ----
    hipMemsetAsync(counts, 0, (N_NODES + 1) * sizeof(int), stream);
    k_hist<<<nb_edges, 256, 0, stream>>>(ei, counts);
    k_slab<<<nb_nodes, 256, 0, stream>>>(counts, gtotal, slab, dinv);
    k_place<<<nb_edges, 256, 0, stream>>>(ei, slab, esrc);   // slab[d] -> row end

    // ---- weights ----
    k_wt2<<<128, 256, 0, stream>>>(W1, WT1, W2, WT2);

    // ---- layer 1 (GEMM reads fp32 x directly) ----
    k_gemm<float><<<nb_gemm, 256, 0, stream>>>(x, WT1, hb, N_NODES);
    k_agg_ln<<<nb_agg, 256, 0, stream>>>(slab, counts, esrc, hb, dinv, b1, g1, be1, nullptr, yb);

    // ---- layer 2 ----
    k_gemm<unsigned short><<<nb_gemm, 256, 0, stream>>>(yb, WT2, hb, N_NODES);
    k_agg_ln<<<nb_agg, 256, 0, stream>>>(slab, counts, esrc, hb, dinv, b2, g2, be2, out, nullptr);
}